// Round 1
// 85.454 us; speedup vs baseline: 1.0053x; 1.0053x over previous
//
#include <hip/hip_runtime.h>

// PoolObj: ball-query (annulus) neighbor-count downsampling + gather.
// B=4, N=4096, D=64, K=2048. Out = concat(new_xyz [B,K,3], new_points [B,K,D]).
//
// Fixed harness overhead (268MB ws 0xAA fill @ ~80% HBM peak = 40.5us, plus
// out poison / input restores / replay gaps) ~= 75us of the measured total;
// our kernels are ~11-14us of it.
//   K1 count_part  : partial annulus counts, j-split (32 chunks), j in PAIRS
//                    via float2 -> v_pk_mul/add_f32 (IEEE-rn, bit-identical;
//                    fp contract OFF). d2 finalized with pk_fma(dot,-2,s):
//                    2*dot is exactly representable (exponent shift), so the
//                    fused form rounds at exactly the same single point the
//                    rn mul+sub chain does -> bit-identical, one pk op less.
//                    Annulus test is ONE unsigned integer range-check on the
//                    float bits (exact: IEEE ordering == int ordering for
//                    positive floats; negatives/denormals map out of range).
//                    Partials stored as BYTES (<=128 per 128-j chunk) in
//                    point-major layout part[b][i][jc] so K2 can read each
//                    point's 32 partials as two contiguous int4s.
//   K2 rank_gather : sums byte partials with v_dot4_u32_u8 (udot4 with
//                    0x01010101 sums 4 bytes/inst; per-point sums <=4096 so
//                    32-bit accum exact) -> LDS keys; ranks 64 owned points;
//                    writes xyz; features go through an LDS transpose tile so
//                    global writes are contiguous float4 runs per point.
// key = cnt<<12 | (4095-i): one int compare == lax.top_k (count desc, index
// asc) order; ranks are a permutation so each output slot written once.
// grid.sync() measured ~45us/sync on gfx950 (round 4) -- kernel boundary is
// the cheap global barrier; do NOT re-fuse.

#pragma clang fp contract(off)

#define BN 4
#define NPTS 4096
#define ND 64
#define KSEL 2048
#define R2 0.0025f   // RADIUS^2
#define M2 0.0004f   // MIN_RADIUS^2

#define IPT 4         // i-points per thread
#define ITILES 4      // NPTS / (256*IPT)
#define JC 32         // j-chunks
#define JCH 128       // NPTS / JC
#define JP (JCH / 2)  // j-pairs per chunk

typedef float f32x2 __attribute__((ext_vector_type(2)));

// Sum the 4 bytes of v into acc (exact while acc+sum < 2^32).
#if __has_builtin(__builtin_amdgcn_udot4)
#define BYTESUM4(v, acc) __builtin_amdgcn_udot4((unsigned)(v), 0x01010101u, (acc), false)
#else
static __device__ __forceinline__ unsigned BYTESUM4(unsigned v, unsigned acc) {
    return acc + (v & 0xFFu) + ((v >> 8) & 0xFFu) + ((v >> 16) & 0xFFu) + (v >> 24);
}
#endif
// Sum all 16 bytes of two int4s onto c.
#define SUM16(a, b, c)                                                        \
    BYTESUM4((unsigned)(b).w, BYTESUM4((unsigned)(b).z,                       \
    BYTESUM4((unsigned)(b).y, BYTESUM4((unsigned)(b).x,                       \
    BYTESUM4((unsigned)(a).w, BYTESUM4((unsigned)(a).z,                       \
    BYTESUM4((unsigned)(a).y, BYTESUM4((unsigned)(a).x, (c)))))))))

static __device__ __forceinline__ f32x2 fma2(f32x2 a, f32x2 b, f32x2 c) {
#if __has_builtin(__builtin_elementwise_fma)
    return __builtin_elementwise_fma(a, b, c);
#else
    f32x2 r;
    r.x = __builtin_fmaf(a.x, b.x, c.x);
    r.y = __builtin_fmaf(a.y, b.y, c.y);
    return r;
#endif
}

// K1: grid = BN*ITILES*JC = 512 blocks (2 blocks/CU).
__global__ __launch_bounds__(256) void count_part_kernel(
        const float* __restrict__ xyz, unsigned char* __restrict__ part) {
    __shared__ float4 sA[JP];   // (x0, x1, y0, y1)
    __shared__ float4 sB[JP];   // (z0, z1, sq0, sq1)
    const int jc = blockIdx.x & (JC - 1);
    const int it = (blockIdx.x >> 5) & (ITILES - 1);
    const int b  = blockIdx.x >> 7;
    const float* base = xyz + (size_t)b * 3 * NPTS;

    if (threadIdx.x < JP) {
        int j0 = jc * JCH + 2 * threadIdx.x;
        float2 xv = *(const float2*)(base + j0);
        float2 yv = *(const float2*)(base + NPTS + j0);
        float2 zv = *(const float2*)(base + 2 * NPTS + j0);
        // sq = (x*x + y*y) + z*z, no FMA contraction (bit-match numpy)
        float sq0 = __fadd_rn(__fadd_rn(__fmul_rn(xv.x, xv.x),
                                        __fmul_rn(yv.x, yv.x)),
                              __fmul_rn(zv.x, zv.x));
        float sq1 = __fadd_rn(__fadd_rn(__fmul_rn(xv.y, xv.y),
                                        __fmul_rn(yv.y, yv.y)),
                              __fmul_rn(zv.y, zv.y));
        sA[threadIdx.x] = make_float4(xv.x, xv.y, yv.x, yv.y);
        sB[threadIdx.x] = make_float4(zv.x, zv.y, sq0, sq1);
    }
    const int ibase = it * 1024 + threadIdx.x;
    f32x2 mx[IPT], my[IPT], mz[IPT], ms[IPT];
    #pragma unroll
    for (int k = 0; k < IPT; ++k) {
        int i = ibase + k * 256;
        float x = base[i], y = base[NPTS + i], z = base[2 * NPTS + i];
        float sq = __fadd_rn(__fadd_rn(__fmul_rn(x, x), __fmul_rn(y, y)),
                             __fmul_rn(z, z));
        mx[k] = (f32x2){x, x};  my[k] = (f32x2){y, y};
        mz[k] = (f32x2){z, z};  ms[k] = (f32x2){sq, sq};
    }
    __syncthreads();

    // Annulus test as one unsigned range check on the float bits:
    //   M2 < d2 < R2  <=>  (unsigned)(bits(d2) - bits(M2) - 1) < RANGE.
    // Exact: positive-float IEEE order == int order; d2<=M2 or negative or
    // >=R2 all fall outside [0, RANGE). No rounding behavior is changed.
    const int      m2i1  = __float_as_int(M2) + 1;
    const unsigned range = (unsigned)(__float_as_int(R2) - __float_as_int(M2)) - 1u;

    int cnt[IPT] = {0, 0, 0, 0};
    const f32x2 ntwo2 = {-2.0f, -2.0f};
    #pragma unroll 2
    for (int jp = 0; jp < JP; ++jp) {
        float4 A = sA[jp], B = sB[jp];
        f32x2 px = {A.x, A.y}, py = {A.z, A.w};
        f32x2 pz = {B.x, B.y}, pw = {B.z, B.w};
        #pragma unroll
        for (int k = 0; k < IPT; ++k) {
            // dot = (x*x' + y*y') + z*z'
            // d2  = fma(dot, -2, sq_i + sq_j)  [== (sq_i+sq_j) - 2*dot in rn:
            //       2*dot is exact, so one rounding either way]
            f32x2 t0  = mx[k] * px;
            f32x2 t1  = my[k] * py;
            f32x2 t2  = mz[k] * pz;
            f32x2 dot = (t0 + t1) + t2;
            f32x2 spw = ms[k] + pw;
            f32x2 d2  = fma2(dot, ntwo2, spw);
            cnt[k] += ((unsigned)(__float_as_int(d2.x) - m2i1) < range) ? 1 : 0;
            cnt[k] += ((unsigned)(__float_as_int(d2.y) - m2i1) < range) ? 1 : 0;
        }
    }
    // point-major byte partials: part[b][i][jc]; cnt <= 128 fits u8.
    unsigned char* pb = part + (size_t)b * NPTS * JC + jc;
    #pragma unroll
    for (int k = 0; k < IPT; ++k)
        pb[(size_t)(ibase + k * 256) * JC] = (unsigned char)cnt[k];
}

// K2: grid = BN*64 = 256 blocks; block owns 64 consecutive i of batch b.
__global__ __launch_bounds__(256) void rank_gather_kernel(
        const float* __restrict__ xyz, const float* __restrict__ points,
        const unsigned char* __restrict__ part, float* __restrict__ out) {
    __shared__ union {
        alignas(16) int skey[NPTS];     // phases A/B: 16 KB keys
        float sfeat[ND][68];            // phase C: transpose tile (pad 68:
    } sh;                               //   68%32==4 -> 2-way LDS = free)
    __shared__ int spr[4][64];
    __shared__ int srank[64];
    const int b     = blockIdx.x >> 6;
    const int tbase = (blockIdx.x & 63) * 64;
    const int tid   = threadIdx.x;

    // ---- phase A: sum byte partials for ALL 4096 points -> LDS keys.
    // Each point = 32 contiguous bytes (two int4 loads); v_dot4_u32_u8
    // against 0x01010101 sums 4 bytes/inst; per-point totals <= 4096 so the
    // 32-bit accumulation is exact. Thread handles 4 consecutive points per
    // round (128B contiguous per lane) -> one int4 LDS key write per round.
    {
        const unsigned char* pbase = part + (size_t)b * NPTS * JC;
        #pragma unroll
        for (int r = 0; r < 4; ++r) {
            const int p4 = r * 1024 + tid * 4;
            const int4* q = (const int4*)(pbase + (size_t)p4 * JC);
            int4 w0 = q[0], w1 = q[1], w2 = q[2], w3 = q[3];
            int4 w4 = q[4], w5 = q[5], w6 = q[6], w7 = q[7];
            unsigned c0 = SUM16(w0, w1, 0u);
            unsigned c1 = SUM16(w2, w3, 0u);
            unsigned c2 = SUM16(w4, w5, 0u);
            unsigned c3 = SUM16(w6, w7, 0u);
            int4 ka;
            ka.x = (int)(c0 << 12) | (NPTS - 1 - (p4 + 0));
            ka.y = (int)(c1 << 12) | (NPTS - 1 - (p4 + 1));
            ka.z = (int)(c2 << 12) | (NPTS - 1 - (p4 + 2));
            ka.w = (int)(c3 << 12) | (NPTS - 1 - (p4 + 3));
            ((int4*)sh.skey)[r * 256 + tid] = ka;
        }
    }
    __syncthreads();

    // ---- phase B: rank own 64 points (wave-broadcast b128 reads, free)
    {
        const int pi = tid & 63;
        const int q  = tid >> 6;                  // 4 j-slices per point
        const int ki = sh.skey[tbase + pi];
        const int4* sk4 = (const int4*)sh.skey;
        int r = 0;
        #pragma unroll 8
        for (int jj = q * 256; jj < q * 256 + 256; ++jj) {
            int4 v = sk4[jj];
            r += (v.x > ki) ? 1 : 0;
            r += (v.y > ki) ? 1 : 0;
            r += (v.z > ki) ? 1 : 0;
            r += (v.w > ki) ? 1 : 0;
        }
        spr[q][pi] = r;
    }
    __syncthreads();

    if (tid < 64) {
        const int rank = spr[0][tid] + spr[1][tid] + spr[2][tid] + spr[3][tid];
        srank[tid] = rank;
        const int i = tbase + tid;
        if (rank < KSEL) {
            const float* xb = xyz + (size_t)b * 3 * NPTS;
            float* o = out + ((size_t)b * KSEL + rank) * 3;
            o[0] = xb[i]; o[1] = xb[NPTS + i]; o[2] = xb[2 * NPTS + i];
        }
    }
    __syncthreads();   // also: skey dead from here, sfeat may overwrite

    // ---- phase C: features via LDS transpose.
    // Load: lane = point (coalesced 256B global reads), LDS 2-way free.
    {
        const int ii = tid & 63;
        const int q  = tid >> 6;
        #pragma unroll
        for (int r16 = 0; r16 < 16; ++r16) {
            const int c = q + 4 * r16;
            sh.sfeat[c][ii] = points[((size_t)b * ND + c) * NPTS + tbase + ii];
        }
    }
    __syncthreads();

    // Write: 4 threads per point, contiguous float4 runs per output row
    // (16 x 64B segments per store inst instead of 64 x 4B scatters).
    {
        const int pt = tid >> 2;        // 0..63
        const int c4 = tid & 3;
        const int rank = srank[pt];
        if (rank < KSEL) {
            float* orow = out + (size_t)BN * KSEL * 3 +
                          ((size_t)b * KSEL + rank) * ND;
            #pragma unroll
            for (int u4 = 0; u4 < 4; ++u4) {
                const int c0 = u4 * 16 + c4 * 4;
                float4 v = make_float4(sh.sfeat[c0 + 0][pt],
                                       sh.sfeat[c0 + 1][pt],
                                       sh.sfeat[c0 + 2][pt],
                                       sh.sfeat[c0 + 3][pt]);
                *(float4*)(orow + c0) = v;
            }
        }
    }
}

extern "C" void kernel_launch(void* const* d_in, const int* in_sizes, int n_in,
                              void* d_out, int out_size, void* d_ws, size_t ws_size,
                              hipStream_t stream) {
    const float* xyz    = (const float*)d_in[0];   // [B, 3, N, 1]
    const float* points = (const float*)d_in[1];   // [B, D, N, 1]
    float* out = (float*)d_out;
    unsigned char* part = (unsigned char*)d_ws;    // 512 KB byte partials

    count_part_kernel<<<BN * ITILES * JC, 256, 0, stream>>>(xyz, part);
    rank_gather_kernel<<<BN * 64, 256, 0, stream>>>(xyz, points, part, out);
}

// Round 2
// 78.429 us; speedup vs baseline: 1.0953x; 1.0896x over previous
//
#include <hip/hip_runtime.h>

// PoolObj: ball-query (annulus) neighbor-count downsampling + gather.
// B=4, N=4096, D=64, K=2048. Out = concat(new_xyz [B,K,3], new_points [B,K,D]).
//
// Fixed harness overhead (268MB ws 0xAA fill @ ~80% HBM peak = 40.5us, plus
// out poison / input restores / replay gaps) ~= 75us of the measured total.
//
// v3: spatial-grid pruning replaces the O(N^2) pair sweep. Points live in the
// unit cube and RADIUS=0.05, so a 16^3 grid (cell 0.0625 > R) means all pairs
// with computed d2 < R2 lie in the 27-cell neighborhood. Pruning is EXACT:
// skipped pairs have true d2 >= 0.0625^2 = 0.0039; the computed-d2 rounding
// error is ~1e-6, nowhere near bridging to R2 = 0.0025. Tested pairs use the
// bit-identical rn chain of the previous (absmax=0) kernel:
//   dot = (x*x' + y*y') + z*z'   (all __fmul_rn / __fadd_rn)
//   d2  = fma(dot, -2, sq_i + sq_j)   [2*dot is exact (exponent shift), so
//         the fused form rounds at the same single point as rn(mul)+rn(sub)]
// Annulus test = ONE unsigned range-check on the float bits (exact: IEEE
// ordering == int ordering for positive floats; neg/zero map out of range).
// cell = floor(16*x) is exact (x in [0,1), *16 is exponent-shift only).
// Counts are integer sums -> bin-atomic order nondeterminism cannot change
// any output bit.
//
//   Ka bin      : 4 blocks x 1024. LDS histogram (16KB) -> block scan ->
//                 scatter into cell-sorted float4(x,y,z,sq) + orig-idx u16 +
//                 cellstart[4097] per batch. LDS zeroed in-block (ws arrives
//                 poisoned every replay; everything read is re-written).
//   Kb count    : 192 blocks; thread = (sorted point, z-slab of 3x3 cells).
//                 Per row the 3 x-neighbor cells are CONSECUTIVE in the flat
//                 cell index -> one [start,end) segment from 2 cellstart
//                 reads. ~27 candidate tests/point vs 4096 (150x less VALU
//                 than the old K1). Partials (3 x u16) by sorted index ->
//                 coalesced stores; 4th slot stays poison, K2 masks it.
//   K2 rank_gather: phase A = 3-partial sum + scatter key to skey[orig]
//                 (orig from sidx); phases B/C unchanged: rank 64 owned
//                 points against all 4096 keys; xyz write; features through
//                 an LDS transpose tile for contiguous float4 output runs.
// key = cnt<<12 | (4095-i): one int compare == lax.top_k (count desc, index
// asc) order; ranks are a permutation so each output slot written once.
// grid.sync() measured ~45us/sync on gfx950 (round 4) -- kernel boundaries
// are the cheap global barriers; do NOT re-fuse.

#pragma clang fp contract(off)

#define BN 4
#define NPTS 4096
#define ND 64
#define KSEL 2048
#define R2 0.0025f   // RADIUS^2
#define M2 0.0004f   // MIN_RADIUS^2
#define NCELL 4096   // 16^3
#define CS_STRIDE 4100

typedef unsigned int u32;
typedef unsigned short u16;

// ws layout (bytes); ws poisoned 0xAA each replay -- every read slot below is
// written first by Ka/Kb in the same replay.
#define OFF_SORTED 0                              // float4 [BN][NPTS] = 256KB
#define OFF_SIDX   262144                         // u16   [BN][NPTS] =  32KB
#define OFF_CS     294912                         // u32   [BN][CS_STRIDE]
#define OFF_PART   360512                         // u16   [BN][NPTS][4] (16B-aligned)

// Ka: one block per batch. Histogram -> scan -> scatter.
__global__ __launch_bounds__(1024) void bin_kernel(
        const float* __restrict__ xyz, float4* __restrict__ sorted,
        u16* __restrict__ sidx, u32* __restrict__ cellstart) {
    __shared__ u32 hist[NCELL];
    __shared__ u32 wtot[16];
    const int b = blockIdx.x;
    const float* base = xyz + (size_t)b * 3 * NPTS;
    const int tid = threadIdx.x;
    for (int k = tid; k < NCELL; k += 1024) hist[k] = 0u;
    __syncthreads();

    u32 crk[4];                       // (cell<<16)|rank-in-cell, both <4096
    #pragma unroll
    for (int k = 0; k < 4; ++k) {
        const int i = tid + k * 1024;
        float x = base[i], y = base[NPTS + i], z = base[2 * NPTS + i];
        // exact: x*16 is an exponent shift for x in [0,1)
        int c = (int)(x * 16.0f) | ((int)(y * 16.0f) << 4)
                                 | ((int)(z * 16.0f) << 8);
        u32 r = atomicAdd(&hist[c], 1u);
        crk[k] = ((u32)c << 16) | r;
    }
    __syncthreads();

    // exclusive scan of hist[4096]: 4 consecutive bins/thread, wave shfl scan,
    // 16 wave totals through LDS.
    u32 v4[4], sum = 0;
    #pragma unroll
    for (int k = 0; k < 4; ++k) { v4[k] = hist[tid * 4 + k]; sum += v4[k]; }
    const int lane = tid & 63, w = tid >> 6;
    u32 incl = sum;
    #pragma unroll
    for (int d = 1; d < 64; d <<= 1) {
        u32 t = __shfl_up(incl, d, 64);
        if (lane >= d) incl += t;
    }
    if (lane == 63) wtot[w] = incl;
    __syncthreads();
    u32 woff = 0;
    #pragma unroll
    for (int ww = 0; ww < 16; ++ww) woff += (ww < w) ? wtot[ww] : 0u;
    u32 run = woff + incl - sum;      // exclusive start of this thread's bins
    #pragma unroll
    for (int k = 0; k < 4; ++k) { u32 h = v4[k]; hist[tid * 4 + k] = run; run += h; }
    __syncthreads();

    // scatter: pos = cellstart[c] + rank. Reload coords (L1-hot), compute sq
    // with the reference rn chain (stored in .w, consumed by Kb's d2).
    u32* csb = cellstart + b * CS_STRIDE;
    #pragma unroll
    for (int k = 0; k < 4; ++k) {
        const int i = tid + k * 1024;
        float x = base[i], y = base[NPTS + i], z = base[2 * NPTS + i];
        float sq = __fadd_rn(__fadd_rn(__fmul_rn(x, x), __fmul_rn(y, y)),
                             __fmul_rn(z, z));
        u32 c = crk[k] >> 16, r = crk[k] & 0xFFFFu;
        u32 pos = hist[c] + r;
        sorted[((size_t)b << 12) + pos] = make_float4(x, y, z, sq);
        sidx[((size_t)b << 12) + pos]   = (u16)i;
    }
    for (int k = tid; k < NCELL; k += 1024) csb[k] = hist[k];
    if (tid == 0) csb[NCELL] = NPTS;
}

// Kb: thread = (batch, z-slab dz in 0..2, sorted point p). 192 blocks.
__global__ __launch_bounds__(256) void count_grid_kernel(
        const float4* __restrict__ sorted, const u32* __restrict__ cellstart,
        u16* __restrict__ part3) {
    const int g  = blockIdx.x * 256 + threadIdx.x;
    const int b  = g / (3 * NPTS);
    const int rg = g - b * 3 * NPTS;
    const int dz = rg >> 12;
    const int p  = rg & (NPTS - 1);

    const float4* sb = sorted + ((size_t)b << 12);
    const float4 v = sb[p];
    const int cx = (int)(v.x * 16.0f);
    const int cy = (int)(v.y * 16.0f);
    const int cz = (int)(v.z * 16.0f);
    const int zz = cz + dz - 1;

    const int      m2i1  = __float_as_int(M2) + 1;
    const unsigned range = (unsigned)(__float_as_int(R2) - __float_as_int(M2)) - 1u;

    u32 cnt = 0;
    if ((unsigned)zz < 16u) {
        const u32* cs = cellstart + b * CS_STRIDE + (zz << 8);
        const int x0  = (cx > 0)  ? cx - 1 : 0;
        const int x1e = ((cx < 15) ? cx + 1 : 15) + 1;
        const int y0  = (cy > 0)  ? cy - 1 : 0;
        const int y1  = (cy < 15) ? cy + 1 : 15;
        for (int y = y0; y <= y1; ++y) {
            // 3 x-neighbor cells are consecutive in the flat index: one
            // [s,e) member segment (flat cellstart is monotone, so x1e=16
            // correctly lands on the next row's start).
            u32 s = cs[(y << 4) + x0];
            u32 e = cs[(y << 4) + x1e];
            for (u32 q = s; q < e; ++q) {
                float4 u = sb[q];
                float dot = __fadd_rn(__fadd_rn(__fmul_rn(v.x, u.x),
                                                __fmul_rn(v.y, u.y)),
                                      __fmul_rn(v.z, u.z));
                float spw = __fadd_rn(v.w, u.w);
                float d2  = __builtin_fmaf(dot, -2.0f, spw);
                // self-pair (q==p): dot==sq exactly, spw==2sq -> d2==0 ->
                // excluded, same as reference.
                cnt += ((unsigned)(__float_as_int(d2) - m2i1) < range) ? 1u : 0u;
            }
        }
    }
    // coalesced 2B stores by sorted index; slot 3 left poisoned (K2 masks).
    part3[((size_t)((b << 12) | p) << 2) + dz] = (u16)cnt;
}

// K2: grid = BN*64 = 256 blocks; block owns 64 consecutive orig-i of batch b.
__global__ __launch_bounds__(256) void rank_gather_kernel(
        const float* __restrict__ xyz, const float* __restrict__ points,
        const u16* __restrict__ part3, const u16* __restrict__ sidx,
        float* __restrict__ out) {
    __shared__ union {
        alignas(16) int skey[NPTS];     // phases A/B: 16 KB keys
        float sfeat[ND][68];            // phase C: transpose tile (pad 68:
    } sh;                               //   68%32==4 -> 2-way LDS = free)
    __shared__ int spr[4][64];
    __shared__ int srank[64];
    const int b     = blockIdx.x >> 6;
    const int tbase = (blockIdx.x & 63) * 64;
    const int tid   = threadIdx.x;

    // ---- phase A: keys = cnt<<12 | (4095-orig), scattered to skey[orig].
    // part3 is by sorted order: uint4 = two points' 3 u16 partials (+1 poison
    // slot each, masked off); sidx pairs give the orig indices.
    {
        const uint4* pq = (const uint4*)(part3 + ((size_t)b << 12) * 4);
        const u32*   sx = (const u32*)(sidx + ((size_t)b << 12));
        #pragma unroll
        for (int r = 0; r < 8; ++r) {
            const int gp = r * 256 + tid;      // pair of sorted points
            uint4 q = pq[gp];
            u32  od = sx[gp];
            u32 c0 = (q.x & 0xFFFFu) + (q.x >> 16) + (q.y & 0xFFFFu);
            u32 c1 = (q.z & 0xFFFFu) + (q.z >> 16) + (q.w & 0xFFFFu);
            int o0 = (int)(od & 0xFFFFu), o1 = (int)(od >> 16);
            sh.skey[o0] = (int)(c0 << 12) | (NPTS - 1 - o0);
            sh.skey[o1] = (int)(c1 << 12) | (NPTS - 1 - o1);
        }
    }
    __syncthreads();

    // ---- phase B: rank own 64 points (wave-broadcast b128 reads, free)
    {
        const int pi = tid & 63;
        const int q  = tid >> 6;                  // 4 j-slices per point
        const int ki = sh.skey[tbase + pi];
        const int4* sk4 = (const int4*)sh.skey;
        int r = 0;
        #pragma unroll 8
        for (int jj = q * 256; jj < q * 256 + 256; ++jj) {
            int4 v = sk4[jj];
            r += (v.x > ki) ? 1 : 0;
            r += (v.y > ki) ? 1 : 0;
            r += (v.z > ki) ? 1 : 0;
            r += (v.w > ki) ? 1 : 0;
        }
        spr[q][pi] = r;
    }
    __syncthreads();

    if (tid < 64) {
        const int rank = spr[0][tid] + spr[1][tid] + spr[2][tid] + spr[3][tid];
        srank[tid] = rank;
        const int i = tbase + tid;
        if (rank < KSEL) {
            const float* xb = xyz + (size_t)b * 3 * NPTS;
            float* o = out + ((size_t)b * KSEL + rank) * 3;
            o[0] = xb[i]; o[1] = xb[NPTS + i]; o[2] = xb[2 * NPTS + i];
        }
    }
    __syncthreads();   // also: skey dead from here, sfeat may overwrite

    // ---- phase C: features via LDS transpose.
    // Load: lane = point (coalesced 256B global reads), LDS 2-way free.
    {
        const int ii = tid & 63;
        const int q  = tid >> 6;
        #pragma unroll
        for (int r16 = 0; r16 < 16; ++r16) {
            const int c = q + 4 * r16;
            sh.sfeat[c][ii] = points[((size_t)b * ND + c) * NPTS + tbase + ii];
        }
    }
    __syncthreads();

    // Write: 4 threads per point, contiguous float4 runs per output row
    // (16 x 64B segments per store inst instead of 64 x 4B scatters).
    {
        const int pt = tid >> 2;        // 0..63
        const int c4 = tid & 3;
        const int rank = srank[pt];
        if (rank < KSEL) {
            float* orow = out + (size_t)BN * KSEL * 3 +
                          ((size_t)b * KSEL + rank) * ND;
            #pragma unroll
            for (int u4 = 0; u4 < 4; ++u4) {
                const int c0 = u4 * 16 + c4 * 4;
                float4 v = make_float4(sh.sfeat[c0 + 0][pt],
                                       sh.sfeat[c0 + 1][pt],
                                       sh.sfeat[c0 + 2][pt],
                                       sh.sfeat[c0 + 3][pt]);
                *(float4*)(orow + c0) = v;
            }
        }
    }
}

extern "C" void kernel_launch(void* const* d_in, const int* in_sizes, int n_in,
                              void* d_out, int out_size, void* d_ws, size_t ws_size,
                              hipStream_t stream) {
    const float* xyz    = (const float*)d_in[0];   // [B, 3, N, 1]
    const float* points = (const float*)d_in[1];   // [B, D, N, 1]
    float* out = (float*)d_out;
    char*  ws  = (char*)d_ws;

    float4* sorted   = (float4*)(ws + OFF_SORTED);
    u16*    sidx     = (u16*)  (ws + OFF_SIDX);
    u32*    cellstart= (u32*)  (ws + OFF_CS);
    u16*    part3    = (u16*)  (ws + OFF_PART);

    bin_kernel       <<<BN, 1024, 0, stream>>>(xyz, sorted, sidx, cellstart);
    count_grid_kernel<<<BN * 3 * NPTS / 256, 256, 0, stream>>>(sorted, cellstart, part3);
    rank_gather_kernel<<<BN * 64, 256, 0, stream>>>(xyz, points, part3, sidx, out);
}

// Round 3
// 78.059 us; speedup vs baseline: 1.1005x; 1.0047x over previous
//
#include <hip/hip_runtime.h>

// PoolObj: ball-query (annulus) neighbor-count downsampling + gather.
// B=4, N=4096, D=64, K=2048. Out = concat(new_xyz [B,K,3], new_points [B,K,D]).
//
// Fixed harness overhead (268MB ws 0xAA fill @ ~80% HBM peak = 41us, plus
// out poison / input restores / replay gaps) ~= 75us of the measured total;
// our kernels are ~3.5us of it (v3 measured 78.43 total).
//
// v4: same exact spatial-grid algorithm as v3 (16^3 cells, cell 0.0625 > R,
// 27-neighborhood pruning is EXACT: skipped pairs have true d2 >= 0.0039 vs
// R2=0.0025, far beyond fp rounding ~1e-6). Tested pairs use the verified
// bit-identical rn chain (absmax=0 in v2/v3):
//   dot = (x*x' + y*y') + z*z'   (__fmul_rn/__fadd_rn)
//   d2  = fma(dot, -2, sq_i + sq_j)   [2*dot exact -> same single rounding]
// Annulus test = ONE unsigned range-check on float bits. cell = floor(16x)
// exact. Counts are integer sums -> bin order cannot change output bits.
//
// v4 structural changes (data movement only, no math change):
//   Kb now assembles the FINAL key (cnt<<12 | 4095-orig) and writes a
//   16KB/batch key array in sorted order: 192-thread blocks = 3 waves =
//   3 z-slabs x 64 points, partials combined in-block via LDS. K2 phase A
//   collapses from {uint4 part3 + sidx reads, 3-way sums, masked poison
//   slot} to 4 coalesced int4 loads + LDS scatter by the orig index that
//   rides inside the key (slot = 4095-(key&0xFFF)).
//   K2 hoists phase-C feature loads (and the tid<64 xyz loads) to kernel
//   start into registers (issue-early/write-late): HBM latency hides under
//   phases A/B; only the ds_write stays after the barrier.
//   Ka keeps coords in registers across hist->scatter and folds the
//   cellstart store into the scan fixup loop.
// key = cnt<<12 | (4095-i): one int compare == lax.top_k (count desc, index
// asc) order; ranks are a permutation so each output slot written once.
// grid.sync() measured ~45us/sync on gfx950 -- kernel boundaries are the
// cheap global barriers; do NOT re-fuse (bin->count->rank each need a
// global sync).

#pragma clang fp contract(off)

#define BN 4
#define NPTS 4096
#define ND 64
#define KSEL 2048
#define R2 0.0025f   // RADIUS^2
#define M2 0.0004f   // MIN_RADIUS^2
#define NCELL 4096   // 16^3
#define CS_STRIDE 4100

typedef unsigned int u32;
typedef unsigned short u16;

// ws layout (bytes); ws poisoned 0xAA each replay -- every slot read below
// is written first by Ka/Kb in the same replay.
#define OFF_SORTED 0                              // float4 [BN][NPTS] = 256KB
#define OFF_SIDX   262144                         // u16   [BN][NPTS] =  32KB
#define OFF_CS     294912                         // u32   [BN][CS_STRIDE]
#define OFF_KEYS   360512                         // u32   [BN][NPTS] =  64KB

// Ka: one block per batch. Histogram -> scan -> scatter.
__global__ __launch_bounds__(1024) void bin_kernel(
        const float* __restrict__ xyz, float4* __restrict__ sorted,
        u16* __restrict__ sidx, u32* __restrict__ cellstart) {
    __shared__ u32 hist[NCELL];
    __shared__ u32 wtot[16];
    const int b = blockIdx.x;
    const float* base = xyz + (size_t)b * 3 * NPTS;
    const int tid = threadIdx.x;
    for (int k = tid; k < NCELL; k += 1024) hist[k] = 0u;
    __syncthreads();

    float xk[4], yk[4], zk[4];
    u32 crk[4];                       // (cell<<16)|rank-in-cell, both <4096
    #pragma unroll
    for (int k = 0; k < 4; ++k) {
        const int i = tid + k * 1024;
        float x = base[i], y = base[NPTS + i], z = base[2 * NPTS + i];
        // exact: x*16 is an exponent shift for x in [0,1)
        int c = (int)(x * 16.0f) | ((int)(y * 16.0f) << 4)
                                 | ((int)(z * 16.0f) << 8);
        u32 r = atomicAdd(&hist[c], 1u);
        crk[k] = ((u32)c << 16) | r;
        xk[k] = x; yk[k] = y; zk[k] = z;
    }
    __syncthreads();

    // exclusive scan of hist[4096]: 4 consecutive bins/thread, wave shfl scan,
    // 16 wave totals through LDS. cellstart written inline with the fixup.
    u32 v4[4], sum = 0;
    #pragma unroll
    for (int k = 0; k < 4; ++k) { v4[k] = hist[tid * 4 + k]; sum += v4[k]; }
    const int lane = tid & 63, w = tid >> 6;
    u32 incl = sum;
    #pragma unroll
    for (int d = 1; d < 64; d <<= 1) {
        u32 t = __shfl_up(incl, d, 64);
        if (lane >= d) incl += t;
    }
    if (lane == 63) wtot[w] = incl;
    __syncthreads();
    u32 woff = 0;
    #pragma unroll
    for (int ww = 0; ww < 16; ++ww) woff += (ww < w) ? wtot[ww] : 0u;
    u32* csb = cellstart + b * CS_STRIDE;
    u32 run = woff + incl - sum;      // exclusive start of this thread's bins
    #pragma unroll
    for (int k = 0; k < 4; ++k) {
        u32 h = v4[k];
        hist[tid * 4 + k] = run;
        csb[tid * 4 + k]  = run;
        run += h;
    }
    if (tid == 0) csb[NCELL] = NPTS;
    __syncthreads();

    // scatter from registers: pos = cellstart[c] + rank; sq via the
    // reference rn chain (stored in .w, consumed by Kb's d2).
    #pragma unroll
    for (int k = 0; k < 4; ++k) {
        float x = xk[k], y = yk[k], z = zk[k];
        float sq = __fadd_rn(__fadd_rn(__fmul_rn(x, x), __fmul_rn(y, y)),
                             __fmul_rn(z, z));
        u32 c = crk[k] >> 16, r = crk[k] & 0xFFFFu;
        u32 pos = hist[c] + r;
        sorted[((size_t)b << 12) + pos] = make_float4(x, y, z, sq);
        sidx[((size_t)b << 12) + pos]   = (u16)(tid + k * 1024);
    }
}

// Kb: block = 192 threads = 3 waves; wave w = z-slab (cz+w-1) for 64
// consecutive sorted points. Partials combined in-block -> final key.
// grid = BN*NPTS/64 = 256 blocks.
__global__ __launch_bounds__(192) void count_key_kernel(
        const float4* __restrict__ sorted, const u32* __restrict__ cellstart,
        const u16* __restrict__ sidx, u32* __restrict__ keys) {
    __shared__ u32 spart[3][64];
    const int tid  = threadIdx.x;
    const int lane = tid & 63;
    const int w    = tid >> 6;            // 0..2 (z-slab)
    const int gp   = blockIdx.x * 64;     // first sorted point of this block
    const int b    = gp >> 12;
    const int p    = (gp & (NPTS - 1)) + lane;

    const float4* sb = sorted + ((size_t)b << 12);
    const float4 v = sb[p];
    const int cx = (int)(v.x * 16.0f);
    const int cy = (int)(v.y * 16.0f);
    const int cz = (int)(v.z * 16.0f);
    const int zz = cz + w - 1;

    const int      m2i1  = __float_as_int(M2) + 1;
    const unsigned range = (unsigned)(__float_as_int(R2) - __float_as_int(M2)) - 1u;

    u32 cnt = 0;
    if ((unsigned)zz < 16u) {
        const u32* cs = cellstart + b * CS_STRIDE + (zz << 8);
        const int x0  = (cx > 0)  ? cx - 1 : 0;
        const int x1e = ((cx < 15) ? cx + 1 : 15) + 1;
        const int y0  = (cy > 0)  ? cy - 1 : 0;
        const int y1  = (cy < 15) ? cy + 1 : 15;
        for (int y = y0; y <= y1; ++y) {
            // 3 x-neighbor cells are consecutive in the flat index: one
            // [s,e) member segment (flat cellstart is monotone; x1e=16
            // correctly lands on the next row's start, csb[4096]=NPTS).
            u32 s = cs[(y << 4) + x0];
            u32 e = cs[(y << 4) + x1e];
            for (u32 q = s; q < e; ++q) {
                float4 u = sb[q];
                float dot = __fadd_rn(__fadd_rn(__fmul_rn(v.x, u.x),
                                                __fmul_rn(v.y, u.y)),
                                      __fmul_rn(v.z, u.z));
                float spw = __fadd_rn(v.w, u.w);
                float d2  = __builtin_fmaf(dot, -2.0f, spw);
                // self-pair (q==p): dot==sq exactly, spw==2sq -> d2==0 ->
                // excluded, same as reference.
                cnt += ((unsigned)(__float_as_int(d2) - m2i1) < range) ? 1u : 0u;
            }
        }
    }
    spart[w][lane] = cnt;
    __syncthreads();
    if (tid < 64) {
        u32 c = spart[0][lane] + spart[1][lane] + spart[2][lane];
        const int orig = sidx[((size_t)b << 12) + p];
        // final key, sorted order; orig index rides in the low 12 bits.
        keys[((size_t)b << 12) + p] = (c << 12) | (u32)(NPTS - 1 - orig);
    }
}

// K2: grid = BN*64 = 256 blocks; block owns 64 consecutive orig-i of batch b.
__global__ __launch_bounds__(256) void rank_gather_kernel(
        const float* __restrict__ xyz, const float* __restrict__ points,
        const u32* __restrict__ keys, float* __restrict__ out) {
    __shared__ union {
        alignas(16) int skey[NPTS];     // phases A/B: 16 KB keys
        float sfeat[ND][68];            // phase C: transpose tile (pad 68:
    } sh;                               //   68%32==4 -> 2-way LDS = free)
    __shared__ int spr[4][64];
    __shared__ int srank[64];
    const int b     = blockIdx.x >> 6;
    const int tbase = (blockIdx.x & 63) * 64;
    const int tid   = threadIdx.x;
    const int ii    = tid & 63;
    const int q     = tid >> 6;

    // ---- issue-early (T14): phase-C feature loads + tid<64 xyz loads into
    // registers NOW; HBM latency hides under phases A/B. ds/global writes
    // stay in their phases.
    float fv[16];
    {
        const float* pb = points + ((size_t)b * ND + q) * NPTS + tbase + ii;
        #pragma unroll
        for (int r16 = 0; r16 < 16; ++r16)
            fv[r16] = pb[(size_t)(4 * r16) * NPTS];
    }
    float x3[3];
    if (tid < 64) {
        const float* xb = xyz + (size_t)b * 3 * NPTS + tbase + tid;
        x3[0] = xb[0]; x3[1] = xb[NPTS]; x3[2] = xb[2 * NPTS];
    }

    // ---- phase A: coalesced key loads, LDS scatter by embedded orig index.
    {
        const int4* kq = (const int4*)(keys + ((size_t)b << 12));
        #pragma unroll
        for (int r = 0; r < 4; ++r) {
            int4 v = kq[r * 256 + tid];
            sh.skey[NPTS - 1 - (v.x & 0xFFF)] = v.x;
            sh.skey[NPTS - 1 - (v.y & 0xFFF)] = v.y;
            sh.skey[NPTS - 1 - (v.z & 0xFFF)] = v.z;
            sh.skey[NPTS - 1 - (v.w & 0xFFF)] = v.w;
        }
    }
    __syncthreads();

    // ---- phase B: rank own 64 points (wave-broadcast b128 reads, free)
    {
        const int ki = sh.skey[tbase + ii];
        const int4* sk4 = (const int4*)sh.skey;
        int r = 0;
        #pragma unroll 8
        for (int jj = q * 256; jj < q * 256 + 256; ++jj) {
            int4 v = sk4[jj];
            r += (v.x > ki) ? 1 : 0;
            r += (v.y > ki) ? 1 : 0;
            r += (v.z > ki) ? 1 : 0;
            r += (v.w > ki) ? 1 : 0;
        }
        spr[q][ii] = r;
    }
    __syncthreads();

    if (tid < 64) {
        const int rank = spr[0][tid] + spr[1][tid] + spr[2][tid] + spr[3][tid];
        srank[tid] = rank;
        if (rank < KSEL) {
            float* o = out + ((size_t)b * KSEL + rank) * 3;
            o[0] = x3[0]; o[1] = x3[1]; o[2] = x3[2];
        }
    }
    __syncthreads();   // also: skey dead from here, sfeat may overwrite

    // ---- phase C: features via LDS transpose (write-late half of T14).
    {
        #pragma unroll
        for (int r16 = 0; r16 < 16; ++r16)
            sh.sfeat[q + 4 * r16][ii] = fv[r16];
    }
    __syncthreads();

    // Write: 4 threads per point, contiguous float4 runs per output row
    // (16 x 64B segments per store inst instead of 64 x 4B scatters).
    {
        const int pt = tid >> 2;        // 0..63
        const int c4 = tid & 3;
        const int rank = srank[pt];
        if (rank < KSEL) {
            float* orow = out + (size_t)BN * KSEL * 3 +
                          ((size_t)b * KSEL + rank) * ND;
            #pragma unroll
            for (int u4 = 0; u4 < 4; ++u4) {
                const int c0 = u4 * 16 + c4 * 4;
                float4 v = make_float4(sh.sfeat[c0 + 0][pt],
                                       sh.sfeat[c0 + 1][pt],
                                       sh.sfeat[c0 + 2][pt],
                                       sh.sfeat[c0 + 3][pt]);
                *(float4*)(orow + c0) = v;
            }
        }
    }
}

extern "C" void kernel_launch(void* const* d_in, const int* in_sizes, int n_in,
                              void* d_out, int out_size, void* d_ws, size_t ws_size,
                              hipStream_t stream) {
    const float* xyz    = (const float*)d_in[0];   // [B, 3, N, 1]
    const float* points = (const float*)d_in[1];   // [B, D, N, 1]
    float* out = (float*)d_out;
    char*  ws  = (char*)d_ws;

    float4* sorted    = (float4*)(ws + OFF_SORTED);
    u16*    sidx      = (u16*)  (ws + OFF_SIDX);
    u32*    cellstart = (u32*)  (ws + OFF_CS);
    u32*    keys      = (u32*)  (ws + OFF_KEYS);

    bin_kernel       <<<BN, 1024, 0, stream>>>(xyz, sorted, sidx, cellstart);
    count_key_kernel <<<BN * NPTS / 64, 192, 0, stream>>>(sorted, cellstart, sidx, keys);
    rank_gather_kernel<<<BN * 64, 256, 0, stream>>>(xyz, points, keys, out);
}

// Round 4
// 76.986 us; speedup vs baseline: 1.1159x; 1.0139x over previous
//
#include <hip/hip_runtime.h>

// PoolObj: ball-query (annulus) neighbor-count downsampling + gather.
// B=4, N=4096, D=64, K=2048. Out = concat(new_xyz [B,K,3], new_points [B,K,D]).
//
// Fixed harness overhead (268MB ws 0xAA fill @ ~80% HBM peak = 41us, plus
// out poison / input restores / replay gaps) ~= 75us of the measured total;
// our kernels are ~3-4us of it (v4 measured 78.06 total).
//
// v5: same exact spatial-grid algorithm (16^3 cells, cell 0.0625 > R; the
// 27-neighborhood pruning is EXACT: skipped pairs have true d2 >= 0.0039 vs
// R2=0.0025, far beyond fp rounding ~1e-6). Tested pairs use the verified
// bit-identical rn chain (absmax=0 in v2..v4):
//   dot = (x*x' + y*y') + z*z'   (__fmul_rn/__fadd_rn)
//   d2  = fma(dot, -2, sq_i + sq_j)   [2*dot exact -> same single rounding]
// Annulus test = ONE unsigned range-check on float bits. cell = floor(16x)
// exact. Counts are integer sums -> bin order cannot change output bits.
//
// v5 structural changes (data movement only, no math change):
//   Kb stores the final key at keys[ORIG] (scattered 4B stores ride in Kb's
//   latency-idle tail); K2 phase A becomes pure linear int4 loads + linear
//   b128 LDS stores (no unpack/scatter).  K2 runs 512 threads: phases A and
//   C-load halve their per-thread latency chains; phase B (the irreducible
//   67M-compare exact ranking, ~1.7us throughput-bound) gets 8 waves of
//   overlap.  Kb hoists the sidx load to kernel start.  Ka zeroes hist via
//   int4 writes.
// key = cnt<<12 | (4095-i): one int compare == lax.top_k (count desc, index
// asc) order; ranks are a permutation so each output slot written once.
// grid.sync() measured ~45us/sync on gfx950 -- kernel boundaries are the
// cheap global barriers; do NOT re-fuse (bin->count->rank each need a
// global sync).

#pragma clang fp contract(off)

#define BN 4
#define NPTS 4096
#define ND 64
#define KSEL 2048
#define R2 0.0025f   // RADIUS^2
#define M2 0.0004f   // MIN_RADIUS^2
#define NCELL 4096   // 16^3
#define CS_STRIDE 4100

typedef unsigned int u32;
typedef unsigned short u16;

// ws layout (bytes); ws poisoned 0xAA each replay -- every slot read below
// is written first by Ka/Kb in the same replay.
#define OFF_SORTED 0                              // float4 [BN][NPTS] = 256KB
#define OFF_SIDX   262144                         // u16   [BN][NPTS] =  32KB
#define OFF_CS     294912                         // u32   [BN][CS_STRIDE]
#define OFF_KEYS   360512                         // u32   [BN][NPTS] =  64KB

// Ka: one block per batch. Histogram -> scan -> scatter.
__global__ __launch_bounds__(1024) void bin_kernel(
        const float* __restrict__ xyz, float4* __restrict__ sorted,
        u16* __restrict__ sidx, u32* __restrict__ cellstart) {
    __shared__ u32 hist[NCELL];
    __shared__ u32 wtot[16];
    const int b = blockIdx.x;
    const float* base = xyz + (size_t)b * 3 * NPTS;
    const int tid = threadIdx.x;
    ((int4*)hist)[tid] = make_int4(0, 0, 0, 0);
    __syncthreads();

    float xk[4], yk[4], zk[4];
    u32 crk[4];                       // (cell<<16)|rank-in-cell, both <4096
    #pragma unroll
    for (int k = 0; k < 4; ++k) {
        const int i = tid + k * 1024;
        float x = base[i], y = base[NPTS + i], z = base[2 * NPTS + i];
        // exact: x*16 is an exponent shift for x in [0,1)
        int c = (int)(x * 16.0f) | ((int)(y * 16.0f) << 4)
                                 | ((int)(z * 16.0f) << 8);
        u32 r = atomicAdd(&hist[c], 1u);
        crk[k] = ((u32)c << 16) | r;
        xk[k] = x; yk[k] = y; zk[k] = z;
    }
    __syncthreads();

    // exclusive scan of hist[4096]: 4 consecutive bins/thread, wave shfl scan,
    // 16 wave totals through LDS. cellstart written inline with the fixup.
    u32 v4[4], sum = 0;
    #pragma unroll
    for (int k = 0; k < 4; ++k) { v4[k] = hist[tid * 4 + k]; sum += v4[k]; }
    const int lane = tid & 63, w = tid >> 6;
    u32 incl = sum;
    #pragma unroll
    for (int d = 1; d < 64; d <<= 1) {
        u32 t = __shfl_up(incl, d, 64);
        if (lane >= d) incl += t;
    }
    if (lane == 63) wtot[w] = incl;
    __syncthreads();
    u32 woff = 0;
    #pragma unroll
    for (int ww = 0; ww < 16; ++ww) woff += (ww < w) ? wtot[ww] : 0u;
    u32* csb = cellstart + b * CS_STRIDE;
    u32 run = woff + incl - sum;      // exclusive start of this thread's bins
    #pragma unroll
    for (int k = 0; k < 4; ++k) {
        u32 h = v4[k];
        hist[tid * 4 + k] = run;
        csb[tid * 4 + k]  = run;
        run += h;
    }
    if (tid == 0) csb[NCELL] = NPTS;
    __syncthreads();

    // scatter from registers: pos = cellstart[c] + rank; sq via the
    // reference rn chain (stored in .w, consumed by Kb's d2).
    #pragma unroll
    for (int k = 0; k < 4; ++k) {
        float x = xk[k], y = yk[k], z = zk[k];
        float sq = __fadd_rn(__fadd_rn(__fmul_rn(x, x), __fmul_rn(y, y)),
                             __fmul_rn(z, z));
        u32 c = crk[k] >> 16, r = crk[k] & 0xFFFFu;
        u32 pos = hist[c] + r;
        sorted[((size_t)b << 12) + pos] = make_float4(x, y, z, sq);
        sidx[((size_t)b << 12) + pos]   = (u16)(tid + k * 1024);
    }
}

// Kb: block = 192 threads = 3 waves; wave w = z-slab (cz+w-1) for 64
// consecutive sorted points. Partials combined in-block -> final key,
// stored at keys[ORIG] so K2's load/LDS-fill is fully linear.
// grid = BN*NPTS/64 = 256 blocks.
__global__ __launch_bounds__(192) void count_key_kernel(
        const float4* __restrict__ sorted, const u32* __restrict__ cellstart,
        const u16* __restrict__ sidx, u32* __restrict__ keys) {
    __shared__ u32 spart[3][64];
    const int tid  = threadIdx.x;
    const int lane = tid & 63;
    const int w    = tid >> 6;            // 0..2 (z-slab)
    const int gp   = blockIdx.x * 64;     // first sorted point of this block
    const int b    = gp >> 12;
    const int p    = (gp & (NPTS - 1)) + lane;

    // issue-early: orig index load rides under the count loop's latency.
    const int orig = sidx[((size_t)b << 12) + p];

    const float4* sb = sorted + ((size_t)b << 12);
    const float4 v = sb[p];
    const int cx = (int)(v.x * 16.0f);
    const int cy = (int)(v.y * 16.0f);
    const int cz = (int)(v.z * 16.0f);
    const int zz = cz + w - 1;

    const int      m2i1  = __float_as_int(M2) + 1;
    const unsigned range = (unsigned)(__float_as_int(R2) - __float_as_int(M2)) - 1u;

    u32 cnt = 0;
    if ((unsigned)zz < 16u) {
        const u32* cs = cellstart + b * CS_STRIDE + (zz << 8);
        const int x0  = (cx > 0)  ? cx - 1 : 0;
        const int x1e = ((cx < 15) ? cx + 1 : 15) + 1;
        const int y0  = (cy > 0)  ? cy - 1 : 0;
        const int y1  = (cy < 15) ? cy + 1 : 15;
        for (int y = y0; y <= y1; ++y) {
            // 3 x-neighbor cells are consecutive in the flat index: one
            // [s,e) member segment (flat cellstart is monotone; x1e=16
            // correctly lands on the next row's start, csb[4096]=NPTS).
            u32 s = cs[(y << 4) + x0];
            u32 e = cs[(y << 4) + x1e];
            for (u32 q = s; q < e; ++q) {
                float4 u = sb[q];
                float dot = __fadd_rn(__fadd_rn(__fmul_rn(v.x, u.x),
                                                __fmul_rn(v.y, u.y)),
                                      __fmul_rn(v.z, u.z));
                float spw = __fadd_rn(v.w, u.w);
                float d2  = __builtin_fmaf(dot, -2.0f, spw);
                // self-pair (q==p): dot==sq exactly, spw==2sq -> d2==0 ->
                // excluded, same as reference.
                cnt += ((unsigned)(__float_as_int(d2) - m2i1) < range) ? 1u : 0u;
            }
        }
    }
    spart[w][lane] = cnt;
    __syncthreads();
    if (tid < 64) {
        u32 c = spart[0][lane] + spart[1][lane] + spart[2][lane];
        // final key stored by ORIG index; low 12 bits encode 4095-orig.
        keys[((size_t)b << 12) + orig] = (c << 12) | (u32)(NPTS - 1 - orig);
    }
}

// K2: grid = BN*64 = 256 blocks x 512 threads; block owns 64 consecutive
// orig-i of batch b.
__global__ __launch_bounds__(512) void rank_gather_kernel(
        const float* __restrict__ xyz, const float* __restrict__ points,
        const u32* __restrict__ keys, float* __restrict__ out) {
    __shared__ union {
        alignas(16) int skey[NPTS];     // phases A/B: 16 KB keys
        float sfeat[ND][68];            // phase C: transpose tile (pad 68:
    } sh;                               //   68%32==4 -> 2-way LDS = free)
    __shared__ int spr[8][64];
    __shared__ int srank[64];
    const int b     = blockIdx.x >> 6;
    const int tbase = (blockIdx.x & 63) * 64;
    const int tid   = threadIdx.x;
    const int ii    = tid & 63;
    const int q     = tid >> 6;          // 0..7

    // ---- issue-early (T14): phase-C feature loads + tid<64 xyz loads into
    // registers NOW; HBM latency hides under phases A/B. ds/global writes
    // stay in their phases.
    float fv[8];
    {
        const float* pb = points + ((size_t)b * ND + q) * NPTS + tbase + ii;
        #pragma unroll
        for (int r8 = 0; r8 < 8; ++r8)
            fv[r8] = pb[(size_t)(8 * r8) * NPTS];
    }
    float x3[3];
    if (tid < 64) {
        const float* xb = xyz + (size_t)b * 3 * NPTS + tbase + tid;
        x3[0] = xb[0]; x3[1] = xb[NPTS]; x3[2] = xb[2 * NPTS];
    }

    // ---- phase A: fully linear -- coalesced int4 loads, b128 LDS stores.
    {
        const int4* kq = (const int4*)(keys + ((size_t)b << 12));
        #pragma unroll
        for (int r = 0; r < 2; ++r)
            ((int4*)sh.skey)[r * 512 + tid] = kq[r * 512 + tid];
    }
    __syncthreads();

    // ---- phase B: rank own 64 points (wave-broadcast b128 reads; 8 slices)
    {
        const int ki = sh.skey[tbase + ii];
        const int4* sk4 = (const int4*)sh.skey;
        int r = 0;
        #pragma unroll 8
        for (int jj = q * 128; jj < q * 128 + 128; ++jj) {
            int4 v = sk4[jj];
            r += (v.x > ki) ? 1 : 0;
            r += (v.y > ki) ? 1 : 0;
            r += (v.z > ki) ? 1 : 0;
            r += (v.w > ki) ? 1 : 0;
        }
        spr[q][ii] = r;
    }
    __syncthreads();

    if (tid < 64) {
        const int rank = spr[0][tid] + spr[1][tid] + spr[2][tid] + spr[3][tid]
                       + spr[4][tid] + spr[5][tid] + spr[6][tid] + spr[7][tid];
        srank[tid] = rank;
        if (rank < KSEL) {
            float* o = out + ((size_t)b * KSEL + rank) * 3;
            o[0] = x3[0]; o[1] = x3[1]; o[2] = x3[2];
        }
    }
    __syncthreads();   // also: skey dead from here, sfeat may overwrite

    // ---- phase C: features via LDS transpose (write-late half of T14).
    {
        #pragma unroll
        for (int r8 = 0; r8 < 8; ++r8)
            sh.sfeat[q + 8 * r8][ii] = fv[r8];
    }
    __syncthreads();

    // Write: 4 threads per point (tid<256 keeps the 2-way-free bank
    // pattern), contiguous float4 runs per output row.
    if (tid < 256) {
        const int pt = tid >> 2;        // 0..63
        const int c4 = tid & 3;
        const int rank = srank[pt];
        if (rank < KSEL) {
            float* orow = out + (size_t)BN * KSEL * 3 +
                          ((size_t)b * KSEL + rank) * ND;
            #pragma unroll
            for (int u4 = 0; u4 < 4; ++u4) {
                const int c0 = u4 * 16 + c4 * 4;
                float4 v = make_float4(sh.sfeat[c0 + 0][pt],
                                       sh.sfeat[c0 + 1][pt],
                                       sh.sfeat[c0 + 2][pt],
                                       sh.sfeat[c0 + 3][pt]);
                *(float4*)(orow + c0) = v;
            }
        }
    }
}

extern "C" void kernel_launch(void* const* d_in, const int* in_sizes, int n_in,
                              void* d_out, int out_size, void* d_ws, size_t ws_size,
                              hipStream_t stream) {
    const float* xyz    = (const float*)d_in[0];   // [B, 3, N, 1]
    const float* points = (const float*)d_in[1];   // [B, D, N, 1]
    float* out = (float*)d_out;
    char*  ws  = (char*)d_ws;

    float4* sorted    = (float4*)(ws + OFF_SORTED);
    u16*    sidx      = (u16*)  (ws + OFF_SIDX);
    u32*    cellstart = (u32*)  (ws + OFF_CS);
    u32*    keys      = (u32*)  (ws + OFF_KEYS);

    bin_kernel        <<<BN, 1024, 0, stream>>>(xyz, sorted, sidx, cellstart);
    count_key_kernel  <<<BN * NPTS / 64, 192, 0, stream>>>(sorted, cellstart, sidx, keys);
    rank_gather_kernel<<<BN * 64, 512, 0, stream>>>(xyz, points, keys, out);
}